// Round 1
// baseline (890.958 us; speedup 1.0000x reference)
//
#include <hip/hip_runtime.h>
#include <hip/hip_bf16.h>

// ---------------------------------------------------------------------------
// KascadeReuseAttention: B=2,S=4096,H=16,D=128, TILE=128, T=32, TOPK=7(+local)
// Pipeline: cvt(x)->bf16 | transpose-cvt(w*) | QKV GEMM (bf16 MFMA) | RoPE |
//           V-transpose | sparse flash attention | out GEMM (f32 out)
// ---------------------------------------------------------------------------

typedef __bf16 bf16_t;
using bf16x8 = __attribute__((ext_vector_type(8))) __bf16;
using bf16x4 = __attribute__((ext_vector_type(4))) __bf16;
using f32x4  = __attribute__((ext_vector_type(4))) float;

typedef const __attribute__((address_space(1))) void* gas_ptr;
typedef __attribute__((address_space(3))) void* las_ptr;

__device__ __forceinline__ void async_copy16(const void* g, void* l) {
  __builtin_amdgcn_global_load_lds((gas_ptr)g, (las_ptr)l, 16, 0, 0);
}

__device__ __forceinline__ f32x4 mfma16x16x32(bf16x8 a, bf16x8 b, f32x4 c) {
  return __builtin_amdgcn_mfma_f32_16x16x32_bf16(a, b, c, 0, 0, 0);
}

// ---------------- elementwise f32 -> bf16 (vectorized) ----------------------
__global__ void cvt_f32_bf16(const float* __restrict__ X, bf16_t* __restrict__ Y) {
  int idx = blockIdx.x * 256 + threadIdx.x;
  float4 v = ((const float4*)X)[idx];
  bf16x4 r;
  r.x = (bf16_t)v.x; r.y = (bf16_t)v.y; r.z = (bf16_t)v.z; r.w = (bf16_t)v.w;
  ((bf16x4*)Y)[idx] = r;
}

// ---------------- weight transpose + convert: W[2048][2048] f32 -> Wt[n][k] bf16
__global__ void wtrans(const float* __restrict__ W, bf16_t* __restrict__ Wt) {
  __shared__ bf16_t t[64][66];   // 66: odd word stride -> conflict-free col read
  const int r0 = blockIdx.x * 64, c0 = blockIdx.y * 64;
  const int tx = threadIdx.x & 63, ty = threadIdx.x >> 6;  // ty in [0,4)
  #pragma unroll
  for (int i = 0; i < 16; ++i) {
    int r = ty + 4 * i;
    t[r][tx] = (bf16_t)W[(size_t)(r0 + r) * 2048 + c0 + tx];
  }
  __syncthreads();
  #pragma unroll
  for (int i = 0; i < 16; ++i) {
    int n = ty + 4 * i;
    Wt[(size_t)(c0 + n) * 2048 + r0 + tx] = t[tx][n];
  }
}

// ---------------- GEMM: C[8192][2048] = A[8192][2048] * Bt[2048][2048]^T ----
// m97 structure: 128x128 tile, BK=32, 4 waves (2x2 of 64x64), gload_lds w=16.
// mode 0: write f32 C row-major (out proj).  mode 1: write bf16 [B,H,S,D].
__global__ __launch_bounds__(256, 2) void gemm_bt(
    const bf16_t* __restrict__ A, const bf16_t* __restrict__ Bt,
    float* __restrict__ Cf, bf16_t* __restrict__ Cq, int mode)
{
  __shared__ bf16_t lA[128 * 32];
  __shared__ bf16_t lB[128 * 32];
  const int bm = blockIdx.x * 128, bn = blockIdx.y * 128;
  const int tid = threadIdx.x;
  const int w = tid >> 6, l = tid & 63;
  const int wr = w >> 1, wc = w & 1;
  const int fr = l & 15, g4 = l >> 4;
  const int srow = l >> 2, scol = (l & 3) * 8;   // staging: 16 rows x 64B per 1KB blk

  f32x4 acc[4][4];
  #pragma unroll
  for (int m = 0; m < 4; ++m)
    #pragma unroll
    for (int n = 0; n < 4; ++n) acc[m][n] = (f32x4){0.f, 0.f, 0.f, 0.f};

  for (int kt = 0; kt < 2048; kt += 32) {
    #pragma unroll
    for (int i = 0; i < 2; ++i) {
      int blk = i * 4 + w;               // 0..7, rows [blk*16, +16)
      int row = blk * 16 + srow;
      async_copy16(A  + (size_t)(bm + row) * 2048 + kt + scol, (char*)lA + blk * 1024);
      async_copy16(Bt + (size_t)(bn + row) * 2048 + kt + scol, (char*)lB + blk * 1024);
    }
    __syncthreads();
    bf16x8 af[4], bfq[4];
    #pragma unroll
    for (int m = 0; m < 4; ++m)
      af[m] = *(const bf16x8*)&lA[(wr * 64 + m * 16 + fr) * 32 + g4 * 8];
    #pragma unroll
    for (int n = 0; n < 4; ++n)
      bfq[n] = *(const bf16x8*)&lB[(wc * 64 + n * 16 + fr) * 32 + g4 * 8];
    #pragma unroll
    for (int m = 0; m < 4; ++m)
      #pragma unroll
      for (int n = 0; n < 4; ++n)
        acc[m][n] = mfma16x16x32(af[m], bfq[n], acc[m][n]);
    __syncthreads();
  }

  #pragma unroll
  for (int m = 0; m < 4; ++m)
    #pragma unroll
    for (int n = 0; n < 4; ++n)
      #pragma unroll
      for (int j = 0; j < 4; ++j) {
        int row = bm + wr * 64 + m * 16 + g4 * 4 + j;   // C/D: row=(l>>4)*4+j
        int col = bn + wc * 64 + n * 16 + fr;           //      col=l&15
        if (mode == 0) {
          Cf[(size_t)row * 2048 + col] = acc[m][n][j];
        } else {
          int b = row >> 12, s = row & 4095, h = col >> 7, d = col & 127;
          Cq[(((size_t)(b * 16 + h)) * 4096 + s) * 128 + d] = (bf16_t)acc[m][n][j];
        }
      }
}

// ---------------- RoPE in place on Q,K [BH=32][S=4096][D=128] bf16 ----------
__global__ void rope_kernel(bf16_t* __restrict__ Q, bf16_t* __restrict__ K,
                            const float* __restrict__ cosT, const float* __restrict__ sinT)
{
  int gid = blockIdx.x * 4 + (threadIdx.x >> 6);   // row id in [0, 2*131072)
  int i = threadIdx.x & 63;
  bf16_t* p = ((gid < 131072) ? Q : K) + (size_t)(gid & 131071) * 128;
  int s = gid & 4095;
  float c = cosT[s * 64 + i], sn = sinT[s * 64 + i];
  float x0 = (float)p[i], x1 = (float)p[i + 64];
  p[i]      = (bf16_t)(x0 * c - x1 * sn);
  p[i + 64] = (bf16_t)(x1 * c + x0 * sn);
}

// ---------------- V transpose: [BH][S][D] -> [BH][D][S] bf16 ----------------
__global__ void vtrans(const bf16_t* __restrict__ Vf, bf16_t* __restrict__ Vt)
{
  __shared__ bf16_t t[128][132];
  const int bh = blockIdx.x, s0 = blockIdx.y * 128;
  const int c = threadIdx.x & 127, half = threadIdx.x >> 7;
  for (int i = 0; i < 64; ++i) {
    int r = half + 2 * i;
    t[r][c] = Vf[((size_t)bh * 4096 + s0 + r) * 128 + c];
  }
  __syncthreads();
  for (int i = 0; i < 64; ++i) {
    int d = half + 2 * i;
    Vt[((size_t)bh * 128 + d) * 4096 + s0 + c] = t[c][d];
  }
}

// ---------------- sparse flash attention ------------------------------------
// block = (b,h,qtile): 4 waves, each owns 32 q-rows. 8 KV tiles (7 anchor+local).
// LDS: Kbuf 32KB (also Q at start, P per-wave later) + Vbuf 32KB. XOR swizzle
// chunk^ (row&7) on 16B chunks of 256B rows (applied at gload source).
__global__ __launch_bounds__(256, 2) void attn_kernel(
    const bf16_t* __restrict__ Qf, const bf16_t* __restrict__ Kf,
    const bf16_t* __restrict__ Vt, const int* __restrict__ anchors,
    bf16_t* __restrict__ outB)   // [B,S,2048] bf16
{
  __shared__ bf16_t Kbuf[16384];
  __shared__ bf16_t Vbuf[16384];
  const int blk = blockIdx.x;
  const int qt = blk & 31, h = (blk >> 5) & 15, b = blk >> 9;
  const int bh = b * 16 + h;
  const int tid = threadIdx.x, w = tid >> 6, l = tid & 63;
  const int fr = l & 15, g4 = l >> 4;
  const float scale = 0.08838834764831845f;   // 1/sqrt(128)

  // ---- stage Q tile (swizzled) into Kbuf ----
  {
    const bf16_t* src = Qf + ((size_t)bh * 4096 + (size_t)qt * 128) * 128;
    #pragma unroll
    for (int i = 0; i < 8; ++i) {
      int bb = i * 4 + w;                 // 32 blocks of 4 rows
      int row = bb * 4 + g4;
      int sc = fr ^ (row & 7);            // pre-swizzled source chunk
      async_copy16(src + (size_t)row * 128 + sc * 8, (char*)Kbuf + bb * 1024);
    }
  }
  __syncthreads();
  bf16x8 aq[2][4];
  #pragma unroll
  for (int m = 0; m < 2; ++m)
    #pragma unroll
    for (int kc = 0; kc < 4; ++kc) {
      int row = w * 32 + m * 16 + fr;
      int ch = (kc * 4 + g4) ^ (row & 7);
      aq[m][kc] = *(const bf16x8*)((const char*)Kbuf + row * 256 + ch * 16);
    }
  __syncthreads();

  float mrun[2][4], lrun[2][4];
  f32x4 o[2][8];
  #pragma unroll
  for (int m = 0; m < 2; ++m)
    #pragma unroll
    for (int j = 0; j < 4; ++j) { mrun[m][j] = -1e30f; lrun[m][j] = 0.f; }
  #pragma unroll
  for (int m = 0; m < 2; ++m)
    #pragma unroll
    for (int n = 0; n < 8; ++n) o[m][n] = (f32x4){0.f, 0.f, 0.f, 0.f};

  const int* anc = anchors + ((size_t)bh * 32 + qt) * 7;

  for (int t = 0; t < 8; ++t) {
    const int tsel = (t < 7) ? anc[t] : qt;
    const int tb = tsel * 128;
    // ---- stage K tile and V^T tile ----
    {
      const bf16_t* ksrc = Kf + ((size_t)bh * 4096 + tb) * 128;
      const bf16_t* vsrc = Vt + (size_t)bh * 128 * 4096 + tb;
      #pragma unroll
      for (int i = 0; i < 8; ++i) {
        int bb = i * 4 + w;
        int row = bb * 4 + g4;
        int sc = fr ^ (row & 7);
        async_copy16(ksrc + (size_t)row * 128 + sc * 8, (char*)Kbuf + bb * 1024);
        async_copy16(vsrc + (size_t)row * 4096 + sc * 8, (char*)Vbuf + bb * 1024);
      }
    }
    __syncthreads();

    // ---- S = Q K^T ----
    f32x4 sc_acc[2][8];
    #pragma unroll
    for (int m = 0; m < 2; ++m)
      #pragma unroll
      for (int n = 0; n < 8; ++n) sc_acc[m][n] = (f32x4){0.f, 0.f, 0.f, 0.f};
    #pragma unroll
    for (int kc = 0; kc < 4; ++kc) {
      bf16x8 bk[8];
      #pragma unroll
      for (int n = 0; n < 8; ++n) {
        int row = n * 16 + fr;
        int ch = (kc * 4 + g4) ^ (row & 7);
        bk[n] = *(const bf16x8*)((const char*)Kbuf + row * 256 + ch * 16);
      }
      #pragma unroll
      for (int m = 0; m < 2; ++m)
        #pragma unroll
        for (int n = 0; n < 8; ++n)
          sc_acc[m][n] = mfma16x16x32(aq[m][kc], bk[n], sc_acc[m][n]);
    }
    __syncthreads();   // all waves done reading K before P overwrites Kbuf

    // ---- mask + online softmax + P -> LDS (per-wave region of Kbuf) ----
    #pragma unroll
    for (int m = 0; m < 2; ++m) {
      #pragma unroll
      for (int j = 0; j < 4; ++j) {
        int qpos = qt * 128 + w * 32 + m * 16 + g4 * 4 + j;
        float pj[8];
        float rowmax = -1e30f;
        #pragma unroll
        for (int n = 0; n < 8; ++n) {
          float lg = sc_acc[m][n][j] * scale;
          int tok = tb + n * 16 + fr;
          if (tok > qpos) lg = -1e10f;
          pj[n] = lg;
          rowmax = fmaxf(rowmax, lg);
        }
        rowmax = fmaxf(rowmax, __shfl_xor(rowmax, 1));
        rowmax = fmaxf(rowmax, __shfl_xor(rowmax, 2));
        rowmax = fmaxf(rowmax, __shfl_xor(rowmax, 4));
        rowmax = fmaxf(rowmax, __shfl_xor(rowmax, 8));
        float mnew = fmaxf(mrun[m][j], rowmax);
        float alpha = __expf(mrun[m][j] - mnew);
        float rsum = 0.f;
        #pragma unroll
        for (int n = 0; n < 8; ++n) { float p = __expf(pj[n] - mnew); pj[n] = p; rsum += p; }
        rsum += __shfl_xor(rsum, 1);
        rsum += __shfl_xor(rsum, 2);
        rsum += __shfl_xor(rsum, 4);
        rsum += __shfl_xor(rsum, 8);
        lrun[m][j] = lrun[m][j] * alpha + rsum;
        mrun[m][j] = mnew;
        #pragma unroll
        for (int nd = 0; nd < 8; ++nd) o[m][nd][j] *= alpha;
        int prow = m * 16 + g4 * 4 + j;
        #pragma unroll
        for (int n = 0; n < 8; ++n) {
          int col = n * 16 + fr;
          int ch = (col >> 3) ^ (prow & 7);
          *((bf16_t*)((char*)Kbuf + w * 8192 + prow * 256 + ch * 16 + (col & 7) * 2))
              = (bf16_t)pj[n];
        }
      }
    }

    // ---- O += P V  (P from own wave region; V^T from Vbuf) ----
    #pragma unroll
    for (int kc = 0; kc < 4; ++kc) {
      bf16x8 ap[2];
      #pragma unroll
      for (int m = 0; m < 2; ++m) {
        int row = m * 16 + fr;
        int ch = (kc * 4 + g4) ^ (row & 7);
        ap[m] = *(const bf16x8*)((const char*)Kbuf + w * 8192 + row * 256 + ch * 16);
      }
      bf16x8 bv[8];
      #pragma unroll
      for (int nd = 0; nd < 8; ++nd) {
        int row = nd * 16 + fr;
        int ch = (kc * 4 + g4) ^ (row & 7);
        bv[nd] = *(const bf16x8*)((const char*)Vbuf + row * 256 + ch * 16);
      }
      #pragma unroll
      for (int m = 0; m < 2; ++m)
        #pragma unroll
        for (int nd = 0; nd < 8; ++nd)
          o[m][nd] = mfma16x16x32(ap[m], bv[nd], o[m][nd]);
    }
    __syncthreads();   // before next tile staging overwrites Kbuf/Vbuf
  }

  // ---- epilogue: O /= l, write [B,S,2048] bf16 ----
  #pragma unroll
  for (int m = 0; m < 2; ++m)
    #pragma unroll
    for (int j = 0; j < 4; ++j) {
      float inv = 1.0f / lrun[m][j];
      int srow = qt * 128 + w * 32 + m * 16 + g4 * 4 + j;
      size_t rbase = ((size_t)b * 4096 + srow) * 2048 + h * 128;
      #pragma unroll
      for (int nd = 0; nd < 8; ++nd)
        outB[rbase + nd * 16 + fr] = (bf16_t)(o[m][nd][j] * inv);
    }
}

// ---------------------------------------------------------------------------
// workspace layout (bytes)
#define OFF_XB   ((size_t)0)            // x bf16            [8192][2048]  32MB
#define OFF_WQT  ((size_t)33554432)     // wq^T bf16         [2048][2048]   8MB
#define OFF_WKT  ((size_t)41943040)
#define OFF_WVT  ((size_t)50331648)
#define OFF_WOT  ((size_t)58720256)
#define OFF_QF   ((size_t)67108864)     // Q bf16 [B,H,S,D]  32MB
#define OFF_KF   ((size_t)100663296)    // K bf16 [B,H,S,D]  32MB
#define OFF_VF   ((size_t)134217728)    // V bf16 [B,H,S,D]  32MB (reused: attn out [B,S,2048])
#define OFF_VT   ((size_t)167772160)    // V^T bf16 [B,H,D,S] 32MB
// total: 192MB

extern "C" void kernel_launch(void* const* d_in, const int* in_sizes, int n_in,
                              void* d_out, int out_size, void* d_ws, size_t ws_size,
                              hipStream_t stream) {
  (void)in_sizes; (void)n_in; (void)out_size; (void)ws_size;
  const float* x    = (const float*)d_in[0];
  const float* wq   = (const float*)d_in[1];
  const float* wk   = (const float*)d_in[2];
  const float* wv   = (const float*)d_in[3];
  const float* wo   = (const float*)d_in[4];
  const float* cosT = (const float*)d_in[5];
  const float* sinT = (const float*)d_in[6];
  const int*   anc  = (const int*)d_in[7];
  float* out = (float*)d_out;
  char* ws = (char*)d_ws;

  bf16_t* xb   = (bf16_t*)(ws + OFF_XB);
  bf16_t* wqt  = (bf16_t*)(ws + OFF_WQT);
  bf16_t* wkt  = (bf16_t*)(ws + OFF_WKT);
  bf16_t* wvt  = (bf16_t*)(ws + OFF_WVT);
  bf16_t* wot  = (bf16_t*)(ws + OFF_WOT);
  bf16_t* Qf   = (bf16_t*)(ws + OFF_QF);
  bf16_t* Kf   = (bf16_t*)(ws + OFF_KF);
  bf16_t* Vf   = (bf16_t*)(ws + OFF_VF);
  bf16_t* Vt   = (bf16_t*)(ws + OFF_VT);
  bf16_t* attnB = (bf16_t*)(ws + OFF_VF);  // alias: Vf dead after vtrans

  // 1. convert x to bf16 (16.8M elems, 4/thread)
  cvt_f32_bf16<<<16384, 256, 0, stream>>>(x, xb);
  // 2. transpose+convert the four weights
  wtrans<<<dim3(32, 32), 256, 0, stream>>>(wq, wqt);
  wtrans<<<dim3(32, 32), 256, 0, stream>>>(wk, wkt);
  wtrans<<<dim3(32, 32), 256, 0, stream>>>(wv, wvt);
  wtrans<<<dim3(32, 32), 256, 0, stream>>>(wo, wot);
  // 3. QKV projections -> [B,H,S,D] bf16
  gemm_bt<<<dim3(64, 16), 256, 0, stream>>>(xb, wqt, nullptr, Qf, 1);
  gemm_bt<<<dim3(64, 16), 256, 0, stream>>>(xb, wkt, nullptr, Kf, 1);
  gemm_bt<<<dim3(64, 16), 256, 0, stream>>>(xb, wvt, nullptr, Vf, 1);
  // 4. RoPE in place on Q and K
  rope_kernel<<<65536, 256, 0, stream>>>(Qf, Kf, cosT, sinT);
  // 5. V -> V^T [B,H,D,S]
  vtrans<<<dim3(32, 32), 256, 0, stream>>>(Vf, Vt);
  // 6. sparse flash attention -> attn [B,S,2048] bf16 (aliases Vf)
  attn_kernel<<<1024, 256, 0, stream>>>(Qf, Kf, Vt, anc, attnB);
  // 7. output projection -> f32 d_out
  gemm_bt<<<dim3(64, 16), 256, 0, stream>>>(attnB, wot, out, nullptr, 0);
}

// Round 2
// 698.272 us; speedup vs baseline: 1.2759x; 1.2759x over previous
//
#include <hip/hip_runtime.h>
#include <hip/hip_bf16.h>

// ---------------------------------------------------------------------------
// KascadeReuseAttention: B=2,S=4096,H=16,D=128, TILE=128, T=32, TOPK=7(+local)
// R2: attention rewritten barrier-free: K/V read direct from global (L2-warm),
// swapped-operand QK^T and PV, P + epilogue staged in per-wave LDS (swizzled).
// ---------------------------------------------------------------------------

typedef __bf16 bf16_t;
using bf16x8 = __attribute__((ext_vector_type(8))) __bf16;
using bf16x4 = __attribute__((ext_vector_type(4))) __bf16;
using f32x4  = __attribute__((ext_vector_type(4))) float;

typedef const __attribute__((address_space(1))) void* gas_ptr;
typedef __attribute__((address_space(3))) void* las_ptr;

__device__ __forceinline__ void async_copy16(const void* g, void* l) {
  __builtin_amdgcn_global_load_lds((gas_ptr)g, (las_ptr)l, 16, 0, 0);
}

__device__ __forceinline__ f32x4 mfma16x16x32(bf16x8 a, bf16x8 b, f32x4 c) {
  return __builtin_amdgcn_mfma_f32_16x16x32_bf16(a, b, c, 0, 0, 0);
}

// ---------------- elementwise f32 -> bf16 (vectorized) ----------------------
__global__ void cvt_f32_bf16(const float* __restrict__ X, bf16_t* __restrict__ Y) {
  int idx = blockIdx.x * 256 + threadIdx.x;
  float4 v = ((const float4*)X)[idx];
  bf16x4 r;
  r.x = (bf16_t)v.x; r.y = (bf16_t)v.y; r.z = (bf16_t)v.z; r.w = (bf16_t)v.w;
  ((bf16x4*)Y)[idx] = r;
}

// ---------------- weight transpose + convert: W[2048][2048] f32 -> Wt[n][k] bf16
__global__ void wtrans(const float* __restrict__ W, bf16_t* __restrict__ Wt) {
  __shared__ bf16_t t[64][66];
  const int r0 = blockIdx.x * 64, c0 = blockIdx.y * 64;
  const int tx = threadIdx.x & 63, ty = threadIdx.x >> 6;
  #pragma unroll
  for (int i = 0; i < 16; ++i) {
    int r = ty + 4 * i;
    t[r][tx] = (bf16_t)W[(size_t)(r0 + r) * 2048 + c0 + tx];
  }
  __syncthreads();
  #pragma unroll
  for (int i = 0; i < 16; ++i) {
    int n = ty + 4 * i;
    Wt[(size_t)(c0 + n) * 2048 + r0 + tx] = t[tx][n];
  }
}

// ---------------- GEMM: C[8192][2048] = A[8192][2048] * Bt[2048][2048]^T ----
__global__ __launch_bounds__(256, 2) void gemm_bt(
    const bf16_t* __restrict__ A, const bf16_t* __restrict__ Bt,
    float* __restrict__ Cf, bf16_t* __restrict__ Cq, int mode)
{
  __shared__ bf16_t lA[128 * 32];
  __shared__ bf16_t lB[128 * 32];
  const int bm = blockIdx.x * 128, bn = blockIdx.y * 128;
  const int tid = threadIdx.x;
  const int w = tid >> 6, l = tid & 63;
  const int wr = w >> 1, wc = w & 1;
  const int fr = l & 15, g4 = l >> 4;
  const int srow = l >> 2, scol = (l & 3) * 8;

  f32x4 acc[4][4];
  #pragma unroll
  for (int m = 0; m < 4; ++m)
    #pragma unroll
    for (int n = 0; n < 4; ++n) acc[m][n] = (f32x4){0.f, 0.f, 0.f, 0.f};

  for (int kt = 0; kt < 2048; kt += 32) {
    #pragma unroll
    for (int i = 0; i < 2; ++i) {
      int blk = i * 4 + w;
      int row = blk * 16 + srow;
      async_copy16(A  + (size_t)(bm + row) * 2048 + kt + scol, (char*)lA + blk * 1024);
      async_copy16(Bt + (size_t)(bn + row) * 2048 + kt + scol, (char*)lB + blk * 1024);
    }
    __syncthreads();
    bf16x8 af[4], bfq[4];
    #pragma unroll
    for (int m = 0; m < 4; ++m)
      af[m] = *(const bf16x8*)&lA[(wr * 64 + m * 16 + fr) * 32 + g4 * 8];
    #pragma unroll
    for (int n = 0; n < 4; ++n)
      bfq[n] = *(const bf16x8*)&lB[(wc * 64 + n * 16 + fr) * 32 + g4 * 8];
    #pragma unroll
    for (int m = 0; m < 4; ++m)
      #pragma unroll
      for (int n = 0; n < 4; ++n)
        acc[m][n] = mfma16x16x32(af[m], bfq[n], acc[m][n]);
    __syncthreads();
  }

  #pragma unroll
  for (int m = 0; m < 4; ++m)
    #pragma unroll
    for (int n = 0; n < 4; ++n)
      #pragma unroll
      for (int j = 0; j < 4; ++j) {
        int row = bm + wr * 64 + m * 16 + g4 * 4 + j;
        int col = bn + wc * 64 + n * 16 + fr;
        if (mode == 0) {
          Cf[(size_t)row * 2048 + col] = acc[m][n][j];
        } else {
          int b = row >> 12, s = row & 4095, h = col >> 7, d = col & 127;
          Cq[(((size_t)(b * 16 + h)) * 4096 + s) * 128 + d] = (bf16_t)acc[m][n][j];
        }
      }
}

// ---------------- RoPE in place on Q,K [BH=32][S=4096][D=128] bf16 ----------
__global__ void rope_kernel(bf16_t* __restrict__ Q, bf16_t* __restrict__ K,
                            const float* __restrict__ cosT, const float* __restrict__ sinT)
{
  int gid = blockIdx.x * 4 + (threadIdx.x >> 6);
  int i = threadIdx.x & 63;
  bf16_t* p = ((gid < 131072) ? Q : K) + (size_t)(gid & 131071) * 128;
  int s = gid & 4095;
  float c = cosT[s * 64 + i], sn = sinT[s * 64 + i];
  float x0 = (float)p[i], x1 = (float)p[i + 64];
  p[i]      = (bf16_t)(x0 * c - x1 * sn);
  p[i + 64] = (bf16_t)(x1 * c + x0 * sn);
}

// ---------------- V transpose: [BH][S][D] -> [BH][D][S] bf16 ----------------
__global__ void vtrans(const bf16_t* __restrict__ Vf, bf16_t* __restrict__ Vt)
{
  __shared__ bf16_t t[128][132];
  const int bh = blockIdx.x, s0 = blockIdx.y * 128;
  const int c = threadIdx.x & 127, half = threadIdx.x >> 7;
  for (int i = 0; i < 64; ++i) {
    int r = half + 2 * i;
    t[r][c] = Vf[((size_t)bh * 4096 + s0 + r) * 128 + c];
  }
  __syncthreads();
  for (int i = 0; i < 64; ++i) {
    int d = half + 2 * i;
    Vt[((size_t)bh * 128 + d) * 4096 + s0 + c] = t[c][d];
  }
}

// ---------------- sparse flash attention (barrier-free) ---------------------
// block = (b,h,qtile): 4 waves, each owns 32 q-rows independently.
// Swapped QK^T: S^T = mfma(Kfrag, Qfrag) -> lane fr owns q-row m*16+fr,
//   regs hold toks n*16+g4*4+j. Softmax: 2 shfl_xor (16,32) per stat.
// P packed bf16x4 -> per-wave 8KB LDS (XOR-swizzled 16B chunks).
// Swapped PV: O^T = mfma(V^T frag (global), P frag (LDS)).
// K/V fragments load direct from global: per instr 16 rows x 64B fully-used
// lines (coalesced). No __syncthreads in the main loop.
__global__ __launch_bounds__(256, 2) void attn_kernel(
    const bf16_t* __restrict__ Qf, const bf16_t* __restrict__ Kf,
    const bf16_t* __restrict__ Vt, const int* __restrict__ anchors,
    bf16_t* __restrict__ outB)   // [B,S,2048] bf16
{
  __shared__ int tsel_s[8];
  __shared__ bf16_t Pbuf[4][4096];   // 8KB per wave
  const int orig = blockIdx.x;
  const int blk = (orig & 7) * 128 + (orig >> 3);   // XCD-chunked swizzle (1024%8==0)
  const int qt = blk & 31, h = (blk >> 5) & 15, b = blk >> 9;
  const int bh = b * 16 + h;
  const int tid = threadIdx.x, w = tid >> 6, l = tid & 63;
  const int fr = l & 15, g4 = l >> 4;
  const float scale = 0.08838834764831845f;   // 1/sqrt(128)

  const int* anc = anchors + ((size_t)bh * 32 + qt) * 7;
  if (tid < 7) tsel_s[tid] = anc[tid];
  if (tid == 7) tsel_s[7] = qt;
  __syncthreads();   // only barrier in the kernel

  const bf16_t* Qbase = Qf + (size_t)bh * 4096 * 128;
  const bf16_t* Kbase = Kf + (size_t)bh * 4096 * 128;
  const bf16_t* Vbase = Vt + (size_t)bh * 128 * 4096;
  char* P = (char*)&Pbuf[w][0];

  // Q fragments for this wave's 32 q-rows (B-operand: col=q, k-chunk g4*8)
  bf16x8 aq[2][4];
  #pragma unroll
  for (int m = 0; m < 2; ++m) {
    int q = qt * 128 + w * 32 + m * 16 + fr;
    #pragma unroll
    for (int kc = 0; kc < 4; ++kc)
      aq[m][kc] = *(const bf16x8*)(Qbase + (size_t)q * 128 + kc * 32 + g4 * 8);
  }

  float mrun[2] = {-1e30f, -1e30f};
  float lrun[2] = {0.f, 0.f};
  f32x4 o[2][8];
  #pragma unroll
  for (int m = 0; m < 2; ++m)
    #pragma unroll
    for (int nd = 0; nd < 8; ++nd) o[m][nd] = (f32x4){0.f, 0.f, 0.f, 0.f};

  for (int t = 0; t < 8; ++t) {
    const int tb = tsel_s[t] * 128;

    // ---- S^T = K Q^T : sc[n][m], D rows = tok (g4*4+j), cols = q (fr) ----
    f32x4 sc[8][2];
    #pragma unroll
    for (int n = 0; n < 8; ++n)
      #pragma unroll
      for (int m = 0; m < 2; ++m) sc[n][m] = (f32x4){0.f, 0.f, 0.f, 0.f};
    #pragma unroll
    for (int kc = 0; kc < 4; ++kc) {
      bf16x8 kf[8];
      #pragma unroll
      for (int n = 0; n < 8; ++n)
        kf[n] = *(const bf16x8*)(Kbase + (size_t)(tb + n * 16 + fr) * 128 + kc * 32 + g4 * 8);
      #pragma unroll
      for (int n = 0; n < 8; ++n)
        #pragma unroll
        for (int m = 0; m < 2; ++m)
          sc[n][m] = mfma16x16x32(kf[n], aq[m][kc], sc[n][m]);
    }

    // ---- mask + online softmax (per m; row q = m*16+fr spread over g4 lanes)
    #pragma unroll
    for (int m = 0; m < 2; ++m) {
      const int qpos = qt * 128 + w * 32 + m * 16 + fr;
      float pv[8][4];
      float rmax = -1e30f;
      #pragma unroll
      for (int n = 0; n < 8; ++n)
        #pragma unroll
        for (int j = 0; j < 4; ++j) {
          float lg = sc[n][m][j] * scale;
          int tok = tb + n * 16 + g4 * 4 + j;
          if (tok > qpos) lg = -1e10f;
          pv[n][j] = lg;
          rmax = fmaxf(rmax, lg);
        }
      rmax = fmaxf(rmax, __shfl_xor(rmax, 16));
      rmax = fmaxf(rmax, __shfl_xor(rmax, 32));
      float mnew = fmaxf(mrun[m], rmax);
      float alpha = __expf(mrun[m] - mnew);
      float rsum = 0.f;
      #pragma unroll
      for (int n = 0; n < 8; ++n)
        #pragma unroll
        for (int j = 0; j < 4; ++j) {
          float p = __expf(pv[n][j] - mnew);
          pv[n][j] = p;
          rsum += p;
        }
      rsum += __shfl_xor(rsum, 16);
      rsum += __shfl_xor(rsum, 32);
      lrun[m] = lrun[m] * alpha + rsum;
      mrun[m] = mnew;
      #pragma unroll
      for (int nd = 0; nd < 8; ++nd) {
        #pragma unroll
        for (int j = 0; j < 4; ++j) o[m][nd][j] *= alpha;
      }
      // pack P[q][tok]: j-consecutive -> bf16x4, swizzled 16B chunks
      const int q = m * 16 + fr;
      #pragma unroll
      for (int n = 0; n < 8; ++n) {
        bf16x4 pk;
        #pragma unroll
        for (int j = 0; j < 4; ++j) pk[j] = (bf16_t)pv[n][j];
        int off = q * 256 + ((((n << 1) | (g4 >> 1)) ^ (q & 7)) << 4) + ((g4 & 1) << 3);
        *(bf16x4*)(P + off) = pk;
      }
    }

    // ---- O^T += V^T P : A = V^T frag (global), B = P frag (LDS) ----
    #pragma unroll
    for (int kc = 0; kc < 4; ++kc) {
      bf16x8 av[8];
      #pragma unroll
      for (int nd = 0; nd < 8; ++nd)
        av[nd] = *(const bf16x8*)(Vbase + (size_t)(nd * 16 + fr) * 4096 + tb + kc * 32 + g4 * 8);
      bf16x8 bp[2];
      #pragma unroll
      for (int m = 0; m < 2; ++m) {
        int q = m * 16 + fr;
        int off = q * 256 + ((((kc << 2) | g4) ^ (q & 7)) << 4);
        bp[m] = *(const bf16x8*)(P + off);
      }
      #pragma unroll
      for (int nd = 0; nd < 8; ++nd)
        #pragma unroll
        for (int m = 0; m < 2; ++m)
          o[m][nd] = mfma16x16x32(av[nd], bp[m], o[m][nd]);
    }
  }

  // ---- epilogue: normalize, pack rows into own LDS region, coalesced store
  #pragma unroll
  for (int m = 0; m < 2; ++m) {
    float inv = 1.0f / lrun[m];
    const int q = m * 16 + fr;
    #pragma unroll
    for (int nd = 0; nd < 8; ++nd) {
      bf16x4 pk;
      #pragma unroll
      for (int j = 0; j < 4; ++j) pk[j] = (bf16_t)(o[m][nd][j] * inv);
      int off = q * 256 + ((((nd << 1) | (g4 >> 1)) ^ (q & 7)) << 4) + ((g4 & 1) << 3);
      *(bf16x4*)(P + off) = pk;
    }
  }
  #pragma unroll
  for (int i = 0; i < 8; ++i) {
    int r = i * 4 + g4;
    int off = r * 256 + ((fr ^ (r & 7)) << 4);
    bf16x8 vrow = *(const bf16x8*)(P + off);
    size_t gaddr = (((size_t)b * 4096 + qt * 128 + w * 32 + r) * 2048) + h * 128 + fr * 8;
    *(bf16x8*)(outB + gaddr) = vrow;
  }
}

// ---------------------------------------------------------------------------
// workspace layout (bytes)
#define OFF_XB   ((size_t)0)            // x bf16            [8192][2048]  32MB
#define OFF_WQT  ((size_t)33554432)     // wq^T bf16         [2048][2048]   8MB
#define OFF_WKT  ((size_t)41943040)
#define OFF_WVT  ((size_t)50331648)
#define OFF_WOT  ((size_t)58720256)
#define OFF_QF   ((size_t)67108864)     // Q bf16 [B,H,S,D]  32MB
#define OFF_KF   ((size_t)100663296)    // K bf16 [B,H,S,D]  32MB
#define OFF_VF   ((size_t)134217728)    // V bf16 [B,H,S,D]  32MB (reused: attn out [B,S,2048])
#define OFF_VT   ((size_t)167772160)    // V^T bf16 [B,H,D,S] 32MB

extern "C" void kernel_launch(void* const* d_in, const int* in_sizes, int n_in,
                              void* d_out, int out_size, void* d_ws, size_t ws_size,
                              hipStream_t stream) {
  (void)in_sizes; (void)n_in; (void)out_size; (void)ws_size;
  const float* x    = (const float*)d_in[0];
  const float* wq   = (const float*)d_in[1];
  const float* wk   = (const float*)d_in[2];
  const float* wv   = (const float*)d_in[3];
  const float* wo   = (const float*)d_in[4];
  const float* cosT = (const float*)d_in[5];
  const float* sinT = (const float*)d_in[6];
  const int*   anc  = (const int*)d_in[7];
  float* out = (float*)d_out;
  char* ws = (char*)d_ws;

  bf16_t* xb   = (bf16_t*)(ws + OFF_XB);
  bf16_t* wqt  = (bf16_t*)(ws + OFF_WQT);
  bf16_t* wkt  = (bf16_t*)(ws + OFF_WKT);
  bf16_t* wvt  = (bf16_t*)(ws + OFF_WVT);
  bf16_t* wot  = (bf16_t*)(ws + OFF_WOT);
  bf16_t* Qf   = (bf16_t*)(ws + OFF_QF);
  bf16_t* Kf   = (bf16_t*)(ws + OFF_KF);
  bf16_t* Vf   = (bf16_t*)(ws + OFF_VF);
  bf16_t* Vt   = (bf16_t*)(ws + OFF_VT);
  bf16_t* attnB = (bf16_t*)(ws + OFF_VF);  // alias: Vf dead after vtrans

  cvt_f32_bf16<<<16384, 256, 0, stream>>>(x, xb);
  wtrans<<<dim3(32, 32), 256, 0, stream>>>(wq, wqt);
  wtrans<<<dim3(32, 32), 256, 0, stream>>>(wk, wkt);
  wtrans<<<dim3(32, 32), 256, 0, stream>>>(wv, wvt);
  wtrans<<<dim3(32, 32), 256, 0, stream>>>(wo, wot);
  gemm_bt<<<dim3(64, 16), 256, 0, stream>>>(xb, wqt, nullptr, Qf, 1);
  gemm_bt<<<dim3(64, 16), 256, 0, stream>>>(xb, wkt, nullptr, Kf, 1);
  gemm_bt<<<dim3(64, 16), 256, 0, stream>>>(xb, wvt, nullptr, Vf, 1);
  rope_kernel<<<65536, 256, 0, stream>>>(Qf, Kf, cosT, sinT);
  vtrans<<<dim3(32, 32), 256, 0, stream>>>(Vf, Vt);
  attn_kernel<<<1024, 256, 0, stream>>>(Qf, Kf, Vt, anc, attnB);
  gemm_bt<<<dim3(64, 16), 256, 0, stream>>>(attnB, wot, out, nullptr, 0);
}